// Round 1
// baseline (793.203 us; speedup 1.0000x reference)
//
#include <hip/hip_runtime.h>
#include <math.h>

#define HH   768
#define WW   768
#define LL   8
#define NPIX (HH*WW)
#define NLVL (NPIX*LL)

#define SIGMAP (1.0f/11.0f)   /* 1/(3+L) */
#define TAUMU  (1.0f/11.0f)   /* 1/(2+PROJ/4) */
#define TAUU   (1.0f/6.0f)
#define LMBDA  0.1f
#define NUC    0.01f

__device__ __forceinline__ float4 ld4(const float* p){ return *reinterpret_cast<const float4*>(p); }
__device__ __forceinline__ void  st4(float* p, float4 v){ *reinterpret_cast<float4*>(p) = v; }

__device__ __forceinline__ void ld8(float* d, const float* s){
  float4 a = ld4(s), b = ld4(s+4);
  d[0]=a.x; d[1]=a.y; d[2]=a.z; d[3]=a.w;
  d[4]=b.x; d[5]=b.y; d[6]=b.z; d[7]=b.w;
}
__device__ __forceinline__ void st8(float* d, const float* s){
  st4(d,   make_float4(s[0],s[1],s[2],s[3]));
  st4(d+4, make_float4(s[4],s[5],s[6],s[7]));
}

// cubic-root parabola projection for one (pixel, z) element
__device__ __forceinline__ void parabola1(float u1, float u2, float u3, float quad,
                                          float& p1n, float& p2n, float& p3n)
{
  float nn = u1*u1 + u2*u2;
  float Bv = 0.25f*nn - quad;
  if (u3 < Bv) {
    float y    = u3 + quad;
    float norm = sqrtf(nn);
    float a    = 0.5f*norm;
    float b    = (2.0f/3.0f)*(1.0f - 0.5f*y);
    float sb   = sqrtf(fmaxf(-b, 0.0f));
    float sb3  = sb*sb*sb;
    float d    = (b < 0.0f) ? (a - sb3)*(a + sb3) : (a*a + b*b*b);
    float v;
    if (d < 0.0f) {
      float sb3s = (sb > 0.0f) ? sb3 : 1.0f;
      float ca   = fminf(fmaxf(a/sb3s, -1.0f), 1.0f);
      v = 2.0f*sb*cosf(acosf(ca)*(1.0f/3.0f));
    } else {
      float sd = sqrtf(d);
      float c  = cbrtf(a + sd);
      v = (c == 0.0f) ? 0.0f : (c - b/c);
    }
    float nsafe = (norm == 0.0f) ? 1.0f : norm;
    float scale = (v + v)/nsafe;                // v/0.5/norm
    p1n = (norm == 0.0f) ? 0.0f : scale*u1;
    p2n = (norm == 0.0f) ? 0.0f : scale*u2;
    p3n = 0.25f*(p1n*p1n + p2n*p2n) - quad;
  } else {
    p1n = u1; p2n = u2; p3n = u3;
  }
}

// ---------------- iteration 1: parabola + l2projection + mu-update ----------
// writes p^1 (3 level arrays) and musum^1 (2 level arrays; the only part of
// mu^1 the iter-2 parabola needs)
__global__ __launch_bounds__(256) void k_iter1(
  const float* __restrict__ ubar, const float* __restrict__ p1,
  const float* __restrict__ p2,   const float* __restrict__ p3,
  const float* __restrict__ s1,   const float* __restrict__ s2,
  const float* __restrict__ mu1,  const float* __restrict__ mu2,
  const float* __restrict__ mb1,  const float* __restrict__ mb2,
  const float* __restrict__ f,
  float* __restrict__ op1, float* __restrict__ op2, float* __restrict__ op3,
  float* __restrict__ oms1, float* __restrict__ oms2)
{
  const int p = blockIdx.x*blockDim.x + threadIdx.x;
  if (p >= NPIX) return;
  const int w  = p % WW;
  const int h  = p / WW;
  const int pr = (w < WW-1) ? p+1  : p;   // clamped -> diff becomes 0
  const int pd = (h < HH-1) ? p+WW : p;

  float ub[8], ubr[8], ubd[8];
  ld8(ub,  ubar + (size_t)p *8);
  ld8(ubr, ubar + (size_t)pr*8);
  ld8(ubd, ubar + (size_t)pd*8);
  float p1v[8], p2v[8], p3v[8];
  ld8(p1v, p1 + (size_t)p*8);
  ld8(p2v, p2 + (size_t)p*8);
  ld8(p3v, p3 + (size_t)p*8);
  const float fv = f[p];

  // ---- phase A: load mu (old), membership sums over combinations ----
  float mu1v[36], mu2v[36];
  {
    const float* a = mu1 + (size_t)p*36;
    const float* b = mu2 + (size_t)p*36;
    #pragma unroll
    for (int c = 0; c < 9; ++c) {
      float4 x = ld4(a + c*4), y = ld4(b + c*4);
      mu1v[c*4+0]=x.x; mu1v[c*4+1]=x.y; mu1v[c*4+2]=x.z; mu1v[c*4+3]=x.w;
      mu2v[c*4+0]=y.x; mu2v[c*4+1]=y.y; mu2v[c*4+2]=y.z; mu2v[c*4+3]=y.w;
    }
  }
  float ms1[8], ms2[8];
  #pragma unroll
  for (int z=0; z<8; ++z){ ms1[z]=0.f; ms2[z]=0.f; }
  {
    int K = 0;
    #pragma unroll
    for (int k1=0; k1<8; ++k1) {
      #pragma unroll
      for (int k2=k1; k2<8; ++k2) {
        #pragma unroll
        for (int z=k1; z<=k2; ++z){ ms1[z]+=mu1v[K]; ms2[z]+=mu2v[K]; }
        ++K;
      }
    }
  }

  // ---- phase B: parabola ----
  float pn1[8], pn2[8], pn3[8];
  #pragma unroll
  for (int z=0; z<8; ++z) {
    float du1 = ubd[z]-ub[z];
    float du2 = ubr[z]-ub[z];
    float du3 = (z<7) ? (ub[z+1]-ub[z]) : 0.f;
    float u1 = p1v[z] + SIGMAP*(du1 + ms1[z]);
    float u2 = p2v[z] + SIGMAP*(du2 + ms2[z]);
    float u3 = p3v[z] + SIGMAP*du3;
    float t  = (float)(z+1)*0.125f - fv;
    float quad = LMBDA*t*t;
    parabola1(u1,u2,u3,quad, pn1[z],pn2[z],pn3[z]);
  }
  st8(op1 + (size_t)p*8, pn1);
  st8(op2 + (size_t)p*8, pn2);
  st8(op3 + (size_t)p*8, pn3);

  // per-pixel prefix sums of the new p (for t[K])
  float pre1[9], pre2[9];
  pre1[0]=0.f; pre2[0]=0.f;
  #pragma unroll
  for (int z=0; z<8; ++z){ pre1[z+1]=pre1[z]+pn1[z]; pre2[z+1]=pre2[z]+pn2[z]; }

  // ---- phase C: l2projection + mu-update + new membership sums ----
  float nms1[8], nms2[8];
  #pragma unroll
  for (int z=0; z<8; ++z){ nms1[z]=0.f; nms2[z]=0.f; }
  {
    const float* a1 = s1  + (size_t)p*36;
    const float* a2 = s2  + (size_t)p*36;
    const float* b1 = mb1 + (size_t)p*36;
    const float* b2 = mb2 + (size_t)p*36;
    float cs1[4], cs2[4], cb1[4], cb2[4];
    int K = 0;
    #pragma unroll
    for (int k1=0; k1<8; ++k1) {
      #pragma unroll
      for (int k2=k1; k2<8; ++k2) {
        if ((K & 3) == 0) {           // compile-time after full unroll
          float4 x = ld4(a1+K), y = ld4(a2+K), u = ld4(b1+K), v = ld4(b2+K);
          cs1[0]=x.x; cs1[1]=x.y; cs1[2]=x.z; cs1[3]=x.w;
          cs2[0]=y.x; cs2[1]=y.y; cs2[2]=y.z; cs2[3]=y.w;
          cb1[0]=u.x; cb1[1]=u.y; cb1[2]=u.z; cb1[3]=u.w;
          cb2[0]=v.x; cb2[1]=v.y; cb2[2]=v.z; cb2[3]=v.w;
        }
        const int j = K & 3;
        float m1 = cs1[j] - cb1[j];   // SIGMAS = 1
        float m2 = cs2[j] - cb2[j];
        float nrm = sqrtf(m1*m1 + m2*m2);
        float s1n, s2n;
        if (nrm > NUC) { float r = NUC/nrm; s1n = m1*r; s2n = m2*r; }
        else           { s1n = m1; s2n = m2; }
        float t1 = pre1[k2+1]-pre1[k1];
        float t2 = pre2[k2+1]-pre2[k1];
        float m1n = mu1v[K] + TAUMU*(s1n - t1);
        float m2n = mu2v[K] + TAUMU*(s2n - t2);
        #pragma unroll
        for (int z=k1; z<=k2; ++z){ nms1[z]+=m1n; nms2[z]+=m2n; }
        ++K;
      }
    }
  }
  st8(oms1 + (size_t)p*8, nms1);
  st8(oms2 + (size_t)p*8, nms2);
}

// ---------------- iteration 2: parabola only, musum read from ws ------------
// in-place update of p1/p2/p3 (each thread touches only its own pixel's p)
__global__ __launch_bounds__(256) void k_parab2(
  const float* __restrict__ ubar,
  float* __restrict__ p1, float* __restrict__ p2, float* __restrict__ p3,
  const float* __restrict__ ms1g, const float* __restrict__ ms2g,
  const float* __restrict__ f)
{
  const int p = blockIdx.x*blockDim.x + threadIdx.x;
  if (p >= NPIX) return;
  const int w  = p % WW;
  const int h  = p / WW;
  const int pr = (w < WW-1) ? p+1  : p;
  const int pd = (h < HH-1) ? p+WW : p;

  float ub[8], ubr[8], ubd[8];
  ld8(ub,  ubar + (size_t)p *8);
  ld8(ubr, ubar + (size_t)pr*8);
  ld8(ubd, ubar + (size_t)pd*8);
  float p1v[8], p2v[8], p3v[8];
  ld8(p1v, p1 + (size_t)p*8);
  ld8(p2v, p2 + (size_t)p*8);
  ld8(p3v, p3 + (size_t)p*8);
  float ms1[8], ms2[8];
  ld8(ms1, ms1g + (size_t)p*8);
  ld8(ms2, ms2g + (size_t)p*8);
  const float fv = f[p];

  float pn1[8], pn2[8], pn3[8];
  #pragma unroll
  for (int z=0; z<8; ++z) {
    float du1 = ubd[z]-ub[z];
    float du2 = ubr[z]-ub[z];
    float du3 = (z<7) ? (ub[z+1]-ub[z]) : 0.f;
    float u1 = p1v[z] + SIGMAP*(du1 + ms1[z]);
    float u2 = p2v[z] + SIGMAP*(du2 + ms2[z]);
    float u3 = p3v[z] + SIGMAP*du3;
    float t  = (float)(z+1)*0.125f - fv;
    float quad = LMBDA*t*t;
    parabola1(u1,u2,u3,quad, pn1[z],pn2[z],pn3[z]);
  }
  st8(p1 + (size_t)p*8, pn1);
  st8(p2 + (size_t)p*8, pn2);
  st8(p3 + (size_t)p*8, pn3);
}

// ---------------- clipping ---------------------------------------------------
// ubarout == nullptr for the final iteration (ubar is dead there)
__global__ __launch_bounds__(256) void k_clip(
  const float* __restrict__ uin,
  const float* __restrict__ p1, const float* __restrict__ p2,
  const float* __restrict__ p3,
  float* __restrict__ uout, float* __restrict__ ubarout)
{
  const int p = blockIdx.x*blockDim.x + threadIdx.x;
  if (p >= NPIX) return;
  const int w  = p % WW;
  const int h  = p / WW;
  const int pu = (h > 0) ? p-WW : p;   // clamped, masked by fh0
  const int pl = (w > 0) ? p-1  : p;

  float uv[8], a1[8], a1u[8], a2[8], a2l[8], a3[8];
  ld8(uv,  uin + (size_t)p *8);
  ld8(a1,  p1  + (size_t)p *8);
  ld8(a1u, p1  + (size_t)pu*8);
  ld8(a2,  p2  + (size_t)p *8);
  ld8(a2l, p2  + (size_t)pl*8);
  ld8(a3,  p3  + (size_t)p *8);

  const float fh1 = (h < HH-1) ? 1.f : 0.f;
  const float fh0 = (h > 0)    ? 1.f : 0.f;
  const float fw1 = (w < WW-1) ? 1.f : 0.f;
  const float fw0 = (w > 0)    ? 1.f : 0.f;

  float un[8], ubn[8];
  #pragma unroll
  for (int z=0; z<8; ++z) {
    float d1 = fh1*a1[z] - fh0*a1u[z];
    float d2 = fw1*a2[z] - fw0*a2l[z];
    float d3 = ((z<7) ? a3[z] : 0.f) - ((z>0) ? a3[z-1] : 0.f);
    float x  = uv[z] + TAUU*(d1+d2+d3);
    x = fminf(fmaxf(x, 0.f), 1.f);
    un[z]  = x;
    ubn[z] = 2.f*x - uv[z];
  }
  st8(uout + (size_t)p*8, un);
  if (ubarout) st8(ubarout + (size_t)p*8, ubn);
}

extern "C" void kernel_launch(void* const* d_in, const int* in_sizes, int n_in,
                              void* d_out, int out_size, void* d_ws, size_t ws_size,
                              hipStream_t stream)
{
  const float* u    = (const float*)d_in[0];
  const float* ubar = (const float*)d_in[1];
  const float* p1   = (const float*)d_in[2];
  const float* p2   = (const float*)d_in[3];
  const float* p3   = (const float*)d_in[4];
  const float* s1   = (const float*)d_in[5];
  const float* s2   = (const float*)d_in[6];
  const float* mu1  = (const float*)d_in[7];
  const float* mu2  = (const float*)d_in[8];
  const float* mb1  = (const float*)d_in[9];
  const float* mb2  = (const float*)d_in[10];
  const float* f    = (const float*)d_in[11];

  float* ws   = (float*)d_ws;           // 6 level-sized buffers = 113.2 MB
  float* wp1  = ws;
  float* wp2  = ws + 1*(size_t)NLVL;
  float* wp3  = ws + 2*(size_t)NLVL;
  float* wms1 = ws + 3*(size_t)NLVL;
  float* wms2 = ws + 4*(size_t)NLVL;
  float* wub  = ws + 5*(size_t)NLVL;
  float* uo   = (float*)d_out;

  dim3 grid(NPIX/256), block(256);
  // iter 1: parabola + l2proj + mu (s/mubar of iter1 are dead beyond this)
  k_iter1 <<<grid, block, 0, stream>>>(ubar,p1,p2,p3,s1,s2,mu1,mu2,mb1,mb2,f,
                                       wp1,wp2,wp3,wms1,wms2);
  // iter 1: clipping -> u^1 (d_out), ubar^1 (ws)
  k_clip  <<<grid, block, 0, stream>>>(u, wp1,wp2,wp3, uo, wub);
  // iter 2: parabola (l2proj/mu of iter2 are dead w.r.t. output u)
  k_parab2<<<grid, block, 0, stream>>>(wub, wp1,wp2,wp3, wms1,wms2, f);
  // iter 2: clipping, u only, in-place on d_out
  k_clip  <<<grid, block, 0, stream>>>(uo, wp1,wp2,wp3, uo, nullptr);
}

// Round 2
// 595.887 us; speedup vs baseline: 1.3311x; 1.3311x over previous
//
#include <hip/hip_runtime.h>
#include <math.h>

#define HH   768
#define WW   768
#define LL   8
#define NPIX (HH*WW)
#define NLVL (NPIX*LL)
#define BLK  128           /* pixels (and threads) per block in k_iter1 */
#define REC  37            /* padded LDS record stride: gcd(37-32,32)=1 -> conflict-free */

#define SIGMAP (1.0f/11.0f)   /* 1/(3+L) */
#define TAUMU  (1.0f/11.0f)   /* 1/(2+PROJ/4) */
#define TAUU   (1.0f/6.0f)
#define LMBDA  0.1f
#define NUC    0.01f

__device__ __forceinline__ float4 ld4(const float* p){ return *reinterpret_cast<const float4*>(p); }
__device__ __forceinline__ void  st4(float* p, float4 v){ *reinterpret_cast<float4*>(p) = v; }

__device__ __forceinline__ void ld8(float* d, const float* s){
  float4 a = ld4(s), b = ld4(s+4);
  d[0]=a.x; d[1]=a.y; d[2]=a.z; d[3]=a.w;
  d[4]=b.x; d[5]=b.y; d[6]=b.z; d[7]=b.w;
}
__device__ __forceinline__ void st8(float* d, const float* s){
  st4(d,   make_float4(s[0],s[1],s[2],s[3]));
  st4(d+4, make_float4(s[4],s[5],s[6],s[7]));
}

// cubic-root parabola projection for one (pixel, z) element
__device__ __forceinline__ void parabola1(float u1, float u2, float u3, float quad,
                                          float& p1n, float& p2n, float& p3n)
{
  float nn = u1*u1 + u2*u2;
  float Bv = 0.25f*nn - quad;
  if (u3 < Bv) {
    float y    = u3 + quad;
    float norm = sqrtf(nn);
    float a    = 0.5f*norm;
    float b    = (2.0f/3.0f)*(1.0f - 0.5f*y);
    float sb   = sqrtf(fmaxf(-b, 0.0f));
    float sb3  = sb*sb*sb;
    float d    = (b < 0.0f) ? (a - sb3)*(a + sb3) : (a*a + b*b*b);
    float v;
    if (d < 0.0f) {
      float sb3s = (sb > 0.0f) ? sb3 : 1.0f;
      float ca   = fminf(fmaxf(a/sb3s, -1.0f), 1.0f);
      v = 2.0f*sb*cosf(acosf(ca)*(1.0f/3.0f));
    } else {
      float sd = sqrtf(d);
      float c  = cbrtf(a + sd);
      v = (c == 0.0f) ? 0.0f : (c - b/c);
    }
    float nsafe = (norm == 0.0f) ? 1.0f : norm;
    float scale = (v + v)/nsafe;                // v/0.5/norm
    p1n = (norm == 0.0f) ? 0.0f : scale*u1;
    p2n = (norm == 0.0f) ? 0.0f : scale*u2;
    p3n = 0.25f*(p1n*p1n + p2n*p2n) - quad;
  } else {
    p1n = u1; p2n = u2; p3n = u3;
  }
}

// stage one proj array (BLK pixels x 36 floats) into LDS records of stride REC.
// Coalesced: lane reads float4 at flat index, scatters to padded record.
// BLK*36/4 = 1152 float4 / BLK threads = 9 per thread.
__device__ __forceinline__ void stage1(const float* __restrict__ g, float* __restrict__ lds, int tid)
{
  #pragma unroll
  for (int j = 0; j < 9; ++j) {
    int g4 = (tid + BLK*j) * 4;          // element index, multiple of 4
    float4 v = ld4(g + g4);
    int pl  = g4 / 36;                   // local pixel (magic-mul)
    int off = g4 - pl*36;
    float* d = lds + pl*REC + off;
    d[0]=v.x; d[1]=v.y; d[2]=v.z; d[3]=v.w;
  }
}

// stage difference a-b (SIGMAS==1) of two proj arrays into LDS records
__device__ __forceinline__ void stage_diff(const float* __restrict__ ga, const float* __restrict__ gb,
                                           float* __restrict__ lds, int tid)
{
  #pragma unroll
  for (int j = 0; j < 9; ++j) {
    int g4 = (tid + BLK*j) * 4;
    float4 a = ld4(ga + g4);
    float4 b = ld4(gb + g4);
    int pl  = g4 / 36;
    int off = g4 - pl*36;
    float* d = lds + pl*REC + off;
    d[0]=a.x-b.x; d[1]=a.y-b.y; d[2]=a.z-b.z; d[3]=a.w-b.w;
  }
}

// ---------------- iteration 1: parabola + l2projection + mu-update ----------
// Key identity: nms[z] = ms_old[z] + TAUMU * sum_{K contains z} (s_n[K] - t[K]),
// so mu is only needed once (phase A) and never re-read in phase C.
__global__ __launch_bounds__(BLK) void k_iter1(
  const float* __restrict__ ubar, const float* __restrict__ p1,
  const float* __restrict__ p2,   const float* __restrict__ p3,
  const float* __restrict__ s1,   const float* __restrict__ s2,
  const float* __restrict__ mu1,  const float* __restrict__ mu2,
  const float* __restrict__ mb1,  const float* __restrict__ mb2,
  const float* __restrict__ f,
  float* __restrict__ op1, float* __restrict__ op2, float* __restrict__ op3,
  float* __restrict__ oms1, float* __restrict__ oms2)
{
  __shared__ float sA[BLK*REC];   // 18.9 KB
  __shared__ float sB[BLK*REC];   // 18.9 KB  -> 37.9 KB total, 4 blocks/CU

  const int tid  = threadIdx.x;
  const int blk0 = blockIdx.x * BLK;          // first pixel of this block
  const int p    = blk0 + tid;                // grid is exact, no bounds check
  const int w  = p % WW;
  const int h  = p / WW;
  const int pr = (w < WW-1) ? p+1  : p;       // clamped -> diff becomes 0
  const int pd = (h < HH-1) ? p+WW : p;

  // ---- stage mu1 -> sA, mu2 -> sB (coalesced, consume-once) ----
  stage1(mu1 + (size_t)blk0*36, sA, tid);
  stage1(mu2 + (size_t)blk0*36, sB, tid);
  __syncthreads();

  // ---- phase A: old-mu membership sums ms[z] = sum_{K: k1<=z<=k2} mu[K] ----
  const float* rA = sA + tid*REC;
  const float* rB = sB + tid*REC;
  float ms1[8], ms2[8];
  #pragma unroll
  for (int z=0; z<8; ++z){ ms1[z]=0.f; ms2[z]=0.f; }
  {
    int K = 0;
    #pragma unroll
    for (int k1=0; k1<8; ++k1) {
      #pragma unroll
      for (int k2=k1; k2<8; ++k2) {
        float v1 = rA[K], v2 = rB[K];
        #pragma unroll
        for (int z=k1; z<=k2; ++z){ ms1[z]+=v1; ms2[z]+=v2; }
        ++K;
      }
    }
  }

  // ---- phase B: parabola (pure registers; overlaps other waves' LDS phase) --
  float ub[8], ubr[8], ubd[8];
  ld8(ub,  ubar + (size_t)p *8);
  ld8(ubr, ubar + (size_t)pr*8);
  ld8(ubd, ubar + (size_t)pd*8);
  float p1v[8], p2v[8], p3v[8];
  ld8(p1v, p1 + (size_t)p*8);
  ld8(p2v, p2 + (size_t)p*8);
  ld8(p3v, p3 + (size_t)p*8);
  const float fv = f[p];

  float pn1[8], pn2[8], pn3[8];
  #pragma unroll
  for (int z=0; z<8; ++z) {
    float du1 = ubd[z]-ub[z];
    float du2 = ubr[z]-ub[z];
    float du3 = (z<7) ? (ub[z+1]-ub[z]) : 0.f;
    float u1 = p1v[z] + SIGMAP*(du1 + ms1[z]);
    float u2 = p2v[z] + SIGMAP*(du2 + ms2[z]);
    float u3 = p3v[z] + SIGMAP*du3;
    float t  = (float)(z+1)*0.125f - fv;
    float quad = LMBDA*t*t;
    parabola1(u1,u2,u3,quad, pn1[z],pn2[z],pn3[z]);
  }
  st8(op1 + (size_t)p*8, pn1);
  st8(op2 + (size_t)p*8, pn2);
  st8(op3 + (size_t)p*8, pn3);

  // per-pixel prefix sums of the new p (for t[K])
  float pre1[9], pre2[9];
  pre1[0]=0.f; pre2[0]=0.f;
  #pragma unroll
  for (int z=0; z<8; ++z){ pre1[z+1]=pre1[z]+pn1[z]; pre2[z+1]=pre2[z]+pn2[z]; }

  // ---- stage m1 = s1-mubar1 -> sA, m2 = s2-mubar2 -> sB ----
  __syncthreads();   // all mu reads done before overwrite
  stage_diff(s1 + (size_t)blk0*36, mb1 + (size_t)blk0*36, sA, tid);
  stage_diff(s2 + (size_t)blk0*36, mb2 + (size_t)blk0*36, sB, tid);
  __syncthreads();

  // ---- phase C: l2projection + mu-update folded into membership sums ----
  float A1[8], A2[8];
  #pragma unroll
  for (int z=0; z<8; ++z){ A1[z]=0.f; A2[z]=0.f; }
  {
    int K = 0;
    #pragma unroll
    for (int k1=0; k1<8; ++k1) {
      #pragma unroll
      for (int k2=k1; k2<8; ++k2) {
        float m1 = rA[K], m2 = rB[K];
        float nrm = sqrtf(m1*m1 + m2*m2);
        float s1n, s2n;
        if (nrm > NUC) { float r = NUC/nrm; s1n = m1*r; s2n = m2*r; }
        else           { s1n = m1; s2n = m2; }
        float d1 = s1n - (pre1[k2+1]-pre1[k1]);
        float d2 = s2n - (pre2[k2+1]-pre2[k1]);
        #pragma unroll
        for (int z=k1; z<=k2; ++z){ A1[z]+=d1; A2[z]+=d2; }
        ++K;
      }
    }
  }
  float nms1[8], nms2[8];
  #pragma unroll
  for (int z=0; z<8; ++z){ nms1[z] = ms1[z] + TAUMU*A1[z]; nms2[z] = ms2[z] + TAUMU*A2[z]; }
  st8(oms1 + (size_t)p*8, nms1);
  st8(oms2 + (size_t)p*8, nms2);
}

// ---------------- iteration 2: parabola only, musum read from ws ------------
__global__ __launch_bounds__(256) void k_parab2(
  const float* __restrict__ ubar,
  float* __restrict__ p1, float* __restrict__ p2, float* __restrict__ p3,
  const float* __restrict__ ms1g, const float* __restrict__ ms2g,
  const float* __restrict__ f)
{
  const int p = blockIdx.x*blockDim.x + threadIdx.x;
  if (p >= NPIX) return;
  const int w  = p % WW;
  const int h  = p / WW;
  const int pr = (w < WW-1) ? p+1  : p;
  const int pd = (h < HH-1) ? p+WW : p;

  float ub[8], ubr[8], ubd[8];
  ld8(ub,  ubar + (size_t)p *8);
  ld8(ubr, ubar + (size_t)pr*8);
  ld8(ubd, ubar + (size_t)pd*8);
  float p1v[8], p2v[8], p3v[8];
  ld8(p1v, p1 + (size_t)p*8);
  ld8(p2v, p2 + (size_t)p*8);
  ld8(p3v, p3 + (size_t)p*8);
  float ms1[8], ms2[8];
  ld8(ms1, ms1g + (size_t)p*8);
  ld8(ms2, ms2g + (size_t)p*8);
  const float fv = f[p];

  float pn1[8], pn2[8], pn3[8];
  #pragma unroll
  for (int z=0; z<8; ++z) {
    float du1 = ubd[z]-ub[z];
    float du2 = ubr[z]-ub[z];
    float du3 = (z<7) ? (ub[z+1]-ub[z]) : 0.f;
    float u1 = p1v[z] + SIGMAP*(du1 + ms1[z]);
    float u2 = p2v[z] + SIGMAP*(du2 + ms2[z]);
    float u3 = p3v[z] + SIGMAP*du3;
    float t  = (float)(z+1)*0.125f - fv;
    float quad = LMBDA*t*t;
    parabola1(u1,u2,u3,quad, pn1[z],pn2[z],pn3[z]);
  }
  st8(p1 + (size_t)p*8, pn1);
  st8(p2 + (size_t)p*8, pn2);
  st8(p3 + (size_t)p*8, pn3);
}

// ---------------- clipping ---------------------------------------------------
__global__ __launch_bounds__(256) void k_clip(
  const float* __restrict__ uin,
  const float* __restrict__ p1, const float* __restrict__ p2,
  const float* __restrict__ p3,
  float* __restrict__ uout, float* __restrict__ ubarout)
{
  const int p = blockIdx.x*blockDim.x + threadIdx.x;
  if (p >= NPIX) return;
  const int w  = p % WW;
  const int h  = p / WW;
  const int pu = (h > 0) ? p-WW : p;
  const int pl = (w > 0) ? p-1  : p;

  float uv[8], a1[8], a1u[8], a2[8], a2l[8], a3[8];
  ld8(uv,  uin + (size_t)p *8);
  ld8(a1,  p1  + (size_t)p *8);
  ld8(a1u, p1  + (size_t)pu*8);
  ld8(a2,  p2  + (size_t)p *8);
  ld8(a2l, p2  + (size_t)pl*8);
  ld8(a3,  p3  + (size_t)p *8);

  const float fh1 = (h < HH-1) ? 1.f : 0.f;
  const float fh0 = (h > 0)    ? 1.f : 0.f;
  const float fw1 = (w < WW-1) ? 1.f : 0.f;
  const float fw0 = (w > 0)    ? 1.f : 0.f;

  float un[8], ubn[8];
  #pragma unroll
  for (int z=0; z<8; ++z) {
    float d1 = fh1*a1[z] - fh0*a1u[z];
    float d2 = fw1*a2[z] - fw0*a2l[z];
    float d3 = ((z<7) ? a3[z] : 0.f) - ((z>0) ? a3[z-1] : 0.f);
    float x  = uv[z] + TAUU*(d1+d2+d3);
    x = fminf(fmaxf(x, 0.f), 1.f);
    un[z]  = x;
    ubn[z] = 2.f*x - uv[z];
  }
  st8(uout + (size_t)p*8, un);
  if (ubarout) st8(ubarout + (size_t)p*8, ubn);
}

extern "C" void kernel_launch(void* const* d_in, const int* in_sizes, int n_in,
                              void* d_out, int out_size, void* d_ws, size_t ws_size,
                              hipStream_t stream)
{
  const float* u    = (const float*)d_in[0];
  const float* ubar = (const float*)d_in[1];
  const float* p1   = (const float*)d_in[2];
  const float* p2   = (const float*)d_in[3];
  const float* p3   = (const float*)d_in[4];
  const float* s1   = (const float*)d_in[5];
  const float* s2   = (const float*)d_in[6];
  const float* mu1  = (const float*)d_in[7];
  const float* mu2  = (const float*)d_in[8];
  const float* mb1  = (const float*)d_in[9];
  const float* mb2  = (const float*)d_in[10];
  const float* f    = (const float*)d_in[11];

  float* ws   = (float*)d_ws;           // 6 level-sized buffers = 113.2 MB
  float* wp1  = ws;
  float* wp2  = ws + 1*(size_t)NLVL;
  float* wp3  = ws + 2*(size_t)NLVL;
  float* wms1 = ws + 3*(size_t)NLVL;
  float* wms2 = ws + 4*(size_t)NLVL;
  float* wub  = ws + 5*(size_t)NLVL;
  float* uo   = (float*)d_out;

  // iter 1: parabola + l2proj + mu (s/mubar of iter1 are dead beyond this)
  k_iter1 <<<dim3(NPIX/BLK), dim3(BLK), 0, stream>>>(
      ubar,p1,p2,p3,s1,s2,mu1,mu2,mb1,mb2,f, wp1,wp2,wp3,wms1,wms2);
  // iter 1: clipping -> u^1 (d_out), ubar^1 (ws)
  k_clip  <<<dim3(NPIX/256), dim3(256), 0, stream>>>(u, wp1,wp2,wp3, uo, wub);
  // iter 2: parabola (l2proj/mu of iter2 are dead w.r.t. output u)
  k_parab2<<<dim3(NPIX/256), dim3(256), 0, stream>>>(wub, wp1,wp2,wp3, wms1,wms2, f);
  // iter 2: clipping, u only, in-place on d_out
  k_clip  <<<dim3(NPIX/256), dim3(256), 0, stream>>>(uo, wp1,wp2,wp3, uo, nullptr);
}